// Round 4
// baseline (416.890 us; speedup 1.0000x reference)
//
#include <hip/hip_runtime.h>
#include <math.h>

#define HIDDEN 8

__global__ __launch_bounds__(256) void edge_decoder_kernel(
    const float* __restrict__ zd,    // [N, 8]
    const float* __restrict__ zm,    // [N, 8]
    const int*   __restrict__ row,   // [E]
    const int*   __restrict__ col,   // [E]
    const float* __restrict__ w1,    // [16, 8] row-major [in][out]
    const float* __restrict__ b1,    // [8]
    const float* __restrict__ w2,    // [8]
    const float* __restrict__ b2,    // [1]
    float* __restrict__ out,
    int E, int N)
{
    int i = blockIdx.x * blockDim.x + threadIdx.x;
    if (i >= E) return;

    // Clamp indices: every memory access below is provably in-bounds.
    int r = row[i];
    int c = col[i];
    if (r < 0) r = 0;
    if (r > N - 1) r = N - 1;
    if (c < 0) c = 0;
    if (c > N - 1) c = N - 1;

    const float* zdr = zd + (size_t)r * HIDDEN;
    const float* zmc = zm + (size_t)c * HIDDEN;

    float z[16];
#pragma unroll
    for (int k = 0; k < HIDDEN; ++k) z[k] = zdr[k];
#pragma unroll
    for (int k = 0; k < HIDDEN; ++k) z[HIDDEN + k] = zmc[k];

    // h = relu(z @ W1 + b1); weight offsets are compile-time constants so
    // the compiler scalarizes them into SGPR operands of v_fma.
    float h[HIDDEN];
#pragma unroll
    for (int j = 0; j < HIDDEN; ++j) h[j] = b1[j];
#pragma unroll
    for (int k = 0; k < 2 * HIDDEN; ++k) {
        float zk = z[k];
#pragma unroll
        for (int j = 0; j < HIDDEN; ++j) {
            h[j] = fmaf(zk, w1[k * HIDDEN + j], h[j]);
        }
    }

    // logit = relu(h) @ w2 + b2
    float logit = b2[0];
#pragma unroll
    for (int j = 0; j < HIDDEN; ++j) {
        float hj = h[j] > 0.0f ? h[j] : 0.0f;
        logit = fmaf(hj, w2[j], logit);
    }

    out[i] = 1.0f / (1.0f + expf(-logit));
}

extern "C" void kernel_launch(void* const* d_in, const int* in_sizes, int n_in,
                              void* d_out, int out_size, void* d_ws, size_t ws_size,
                              hipStream_t stream) {
    const float* zd  = (const float*)d_in[0];
    const float* zm  = (const float*)d_in[1];
    const int*   eli = (const int*)d_in[2];   // [2, E] flat: row then col
    const float* w1  = (const float*)d_in[3];
    const float* b1  = (const float*)d_in[4];
    const float* w2  = (const float*)d_in[5];
    const float* b2  = (const float*)d_in[6];
    float* out = (float*)d_out;

    int E = out_size;                 // 16,000,000
    int N = in_sizes[0] / HIDDEN;     // 100,000
    if (E <= 0 || N <= 0) return;

    const int* row = eli;
    const int* col = eli + E;

    const int block = 256;
    int grid = (E + block - 1) / block;
    edge_decoder_kernel<<<grid, block, 0, stream>>>(zd, zm, row, col,
                                                    w1, b1, w2, b2, out, E, N);
}

// Round 6
// 349.477 us; speedup vs baseline: 1.1929x; 1.1929x over previous
//
#include <hip/hip_runtime.h>
#include <math.h>

#define HIDDEN 8

// ---- table conversion: fp32 [N,8] -> bf16-packed [N,4] dwords -----------
__global__ __launch_bounds__(256) void convert_kernel(
    const float* __restrict__ zd, const float* __restrict__ zm,
    unsigned* __restrict__ zdb, unsigned* __restrict__ zmb, int npairs)
{
    // each thread packs one dword = two bf16 values
    int i = blockIdx.x * blockDim.x + threadIdx.x;
    const float* src;
    unsigned* dst;
    int p;
    if (i < npairs) {
        src = zd; dst = zdb; p = i;
    } else if (i < 2 * npairs) {
        src = zm; dst = zmb; p = i - npairs;
    } else {
        return;
    }
    union { float f; unsigned u; } lo, hi;
    lo.f = src[2 * p];
    hi.f = src[2 * p + 1];
    unsigned lr = (lo.u + 0x7fffu + ((lo.u >> 16) & 1u)) >> 16;   // rne
    unsigned hr = (hi.u + 0x7fffu + ((hi.u >> 16) & 1u)) & 0xffff0000u;
    dst[p] = lr | hr;
}

// ---- main kernel: 1 edge per thread, scalar loads -----------------------
__global__ __launch_bounds__(256) void edge_decoder_bf16_kernel(
    const unsigned* __restrict__ zdb,   // [N,4] packed bf16 pairs
    const unsigned* __restrict__ zmb,   // [N,4]
    const int* __restrict__ row, const int* __restrict__ col,
    const float* __restrict__ w1, const float* __restrict__ b1,
    const float* __restrict__ w2, const float* __restrict__ b2,
    float* __restrict__ out, int E, int N)
{
    int i = blockIdx.x * blockDim.x + threadIdx.x;
    if (i >= E) return;

    int r = row[i];
    int c = col[i];
    if (r < 0) r = 0;
    if (r > N - 1) r = N - 1;
    if (c < 0) c = 0;
    if (c > N - 1) c = N - 1;

    const unsigned* ar = zdb + (size_t)r * 4;
    const unsigned* mc = zmb + (size_t)c * 4;

    unsigned pk[8];
#pragma unroll
    for (int k = 0; k < 4; ++k) pk[k] = ar[k];
#pragma unroll
    for (int k = 0; k < 4; ++k) pk[4 + k] = mc[k];

    float z[16];
#pragma unroll
    for (int k = 0; k < 8; ++k) {
        union { unsigned u; float f; } a, b;
        a.u = pk[k] << 16;
        b.u = pk[k] & 0xffff0000u;
        z[2 * k] = a.f;
        z[2 * k + 1] = b.f;
    }

    float h[HIDDEN];
#pragma unroll
    for (int j = 0; j < HIDDEN; ++j) h[j] = b1[j];
#pragma unroll
    for (int k = 0; k < 2 * HIDDEN; ++k) {
        float zk = z[k];
#pragma unroll
        for (int j = 0; j < HIDDEN; ++j)
            h[j] = fmaf(zk, w1[k * HIDDEN + j], h[j]);
    }

    float logit = b2[0];
#pragma unroll
    for (int j = 0; j < HIDDEN; ++j) {
        float hj = h[j] > 0.0f ? h[j] : 0.0f;
        logit = fmaf(hj, w2[j], logit);
    }

    out[i] = 1.0f / (1.0f + expf(-logit));
}

// ---- fallback: fp32 gather (only if workspace too small) ----------------
__global__ __launch_bounds__(256) void edge_decoder_f32_kernel(
    const float* __restrict__ zd, const float* __restrict__ zm,
    const int* __restrict__ row, const int* __restrict__ col,
    const float* __restrict__ w1, const float* __restrict__ b1,
    const float* __restrict__ w2, const float* __restrict__ b2,
    float* __restrict__ out, int E, int N)
{
    int i = blockIdx.x * blockDim.x + threadIdx.x;
    if (i >= E) return;
    int r = row[i];
    int c = col[i];
    if (r < 0) r = 0;
    if (r > N - 1) r = N - 1;
    if (c < 0) c = 0;
    if (c > N - 1) c = N - 1;
    const float* zdr = zd + (size_t)r * HIDDEN;
    const float* zmc = zm + (size_t)c * HIDDEN;
    float z[16];
#pragma unroll
    for (int k = 0; k < HIDDEN; ++k) z[k] = zdr[k];
#pragma unroll
    for (int k = 0; k < HIDDEN; ++k) z[HIDDEN + k] = zmc[k];
    float h[HIDDEN];
#pragma unroll
    for (int j = 0; j < HIDDEN; ++j) h[j] = b1[j];
#pragma unroll
    for (int k = 0; k < 2 * HIDDEN; ++k) {
        float zk = z[k];
#pragma unroll
        for (int j = 0; j < HIDDEN; ++j)
            h[j] = fmaf(zk, w1[k * HIDDEN + j], h[j]);
    }
    float logit = b2[0];
#pragma unroll
    for (int j = 0; j < HIDDEN; ++j) {
        float hj = h[j] > 0.0f ? h[j] : 0.0f;
        logit = fmaf(hj, w2[j], logit);
    }
    out[i] = 1.0f / (1.0f + expf(-logit));
}

extern "C" void kernel_launch(void* const* d_in, const int* in_sizes, int n_in,
                              void* d_out, int out_size, void* d_ws, size_t ws_size,
                              hipStream_t stream) {
    const float* zd  = (const float*)d_in[0];
    const float* zm  = (const float*)d_in[1];
    const int*   eli = (const int*)d_in[2];   // [2, E] flat: row then col
    const float* w1  = (const float*)d_in[3];
    const float* b1  = (const float*)d_in[4];
    const float* w2  = (const float*)d_in[5];
    const float* b2  = (const float*)d_in[6];
    float* out = (float*)d_out;

    int E = out_size;                 // 16,000,000
    int N = in_sizes[0] / HIDDEN;     // 100,000
    if (E <= 0 || N <= 0) return;

    const int* row = eli;
    const int* col = eli + E;
    const int block = 256;

    size_t tbl_bytes = (size_t)N * 4 * sizeof(unsigned);
    if (ws_size >= 2 * tbl_bytes) {
        unsigned* zdb = (unsigned*)d_ws;
        unsigned* zmb = zdb + (size_t)N * 4;

        int npairs = N * 4;           // dword pairs per table
        int cgrid = (2 * npairs + block - 1) / block;
        convert_kernel<<<cgrid, block, 0, stream>>>(zd, zm, zdb, zmb, npairs);

        int grid = (E + block - 1) / block;
        edge_decoder_bf16_kernel<<<grid, block, 0, stream>>>(
            zdb, zmb, row, col, w1, b1, w2, b2, out, E, N);
    } else {
        int grid = (E + block - 1) / block;
        edge_decoder_f32_kernel<<<grid, block, 0, stream>>>(
            zd, zm, row, col, w1, b1, w2, b2, out, E, N);
    }
}

// Round 7
// 330.548 us; speedup vs baseline: 1.2612x; 1.0573x over previous
//
#include <hip/hip_runtime.h>
#include <math.h>

#define HIDDEN 8

// ---- table conversion: fp32 [N,8] -> bf16-packed [N,4] dwords -----------
__global__ __launch_bounds__(256) void convert_kernel(
    const float* __restrict__ zd, const float* __restrict__ zm,
    unsigned* __restrict__ zdb, unsigned* __restrict__ zmb, int npairs)
{
    int i = blockIdx.x * blockDim.x + threadIdx.x;
    const float* src;
    unsigned* dst;
    int p;
    if (i < npairs) {
        src = zd; dst = zdb; p = i;
    } else if (i < 2 * npairs) {
        src = zm; dst = zmb; p = i - npairs;
    } else {
        return;
    }
    union { float f; unsigned u; } lo, hi;
    lo.f = src[2 * p];
    hi.f = src[2 * p + 1];
    unsigned lr = (lo.u + 0x7fffu + ((lo.u >> 16) & 1u)) >> 16;   // rne
    unsigned hr = (hi.u + 0x7fffu + ((hi.u >> 16) & 1u)) & 0xffff0000u;
    dst[p] = lr | hr;
}

// ---- MLP on one edge's 8 packed dwords ----------------------------------
__device__ __forceinline__ float edge_mlp(
    const unsigned* pk,   // 8 packed bf16-pair dwords (registers)
    const float* __restrict__ w1, const float* __restrict__ b1,
    const float* __restrict__ w2, float b2v)
{
    float z[16];
#pragma unroll
    for (int k = 0; k < 8; ++k) {
        union { unsigned u; float f; } a, b;
        a.u = pk[k] << 16;
        b.u = pk[k] & 0xffff0000u;
        z[2 * k] = a.f;
        z[2 * k + 1] = b.f;
    }
    float h[HIDDEN];
#pragma unroll
    for (int j = 0; j < HIDDEN; ++j) h[j] = b1[j];
#pragma unroll
    for (int k = 0; k < 2 * HIDDEN; ++k) {
        float zk = z[k];
#pragma unroll
        for (int j = 0; j < HIDDEN; ++j)
            h[j] = fmaf(zk, w1[k * HIDDEN + j], h[j]);
    }
    float logit = b2v;
#pragma unroll
    for (int j = 0; j < HIDDEN; ++j) {
        float hj = h[j] > 0.0f ? h[j] : 0.0f;
        logit = fmaf(hj, w2[j], logit);
    }
    return 1.0f / (1.0f + expf(-logit));
}

// ---- main kernel: 4 edges per thread, scalar loads (compiler-merged) ----
__global__ __launch_bounds__(256) void edge_decoder_bf16x4_kernel(
    const unsigned* __restrict__ zdb,   // [N,4] packed bf16 pairs
    const unsigned* __restrict__ zmb,   // [N,4]
    const int* __restrict__ row, const int* __restrict__ col,
    const float* __restrict__ w1, const float* __restrict__ b1,
    const float* __restrict__ w2, const float* __restrict__ b2,
    float* __restrict__ out, int E, int N)
{
    int t = blockIdx.x * blockDim.x + threadIdx.x;
    int base = t * 4;
    if (base >= E) return;

    float b2v = b2[0];

    if (base + 3 < E) {
        // 4 consecutive indices from each array (merge -> dwordx4)
        int r[4], c[4];
#pragma unroll
        for (int e = 0; e < 4; ++e) r[e] = row[base + e];
#pragma unroll
        for (int e = 0; e < 4; ++e) c[e] = col[base + e];
#pragma unroll
        for (int e = 0; e < 4; ++e) {
            if (r[e] < 0) r[e] = 0;
            if (r[e] > N - 1) r[e] = N - 1;
            if (c[e] < 0) c[e] = 0;
            if (c[e] > N - 1) c[e] = N - 1;
        }

        // issue all 8 row gathers (32 dwords -> 8 dwordx4) before compute
        unsigned pk[4][8];
#pragma unroll
        for (int e = 0; e < 4; ++e) {
            const unsigned* ar = zdb + (size_t)r[e] * 4;
#pragma unroll
            for (int k = 0; k < 4; ++k) pk[e][k] = ar[k];
        }
#pragma unroll
        for (int e = 0; e < 4; ++e) {
            const unsigned* mc = zmb + (size_t)c[e] * 4;
#pragma unroll
            for (int k = 0; k < 4; ++k) pk[e][4 + k] = mc[k];
        }

        float res[4];
#pragma unroll
        for (int e = 0; e < 4; ++e)
            res[e] = edge_mlp(pk[e], w1, b1, w2, b2v);

        // contiguous scalar stores (merge -> dwordx4)
#pragma unroll
        for (int e = 0; e < 4; ++e) out[base + e] = res[e];
    } else {
        for (int i = base; i < E; ++i) {
            int r = row[i];
            int c = col[i];
            if (r < 0) r = 0;
            if (r > N - 1) r = N - 1;
            if (c < 0) c = 0;
            if (c > N - 1) c = N - 1;
            unsigned pk[8];
            const unsigned* ar = zdb + (size_t)r * 4;
            const unsigned* mc = zmb + (size_t)c * 4;
#pragma unroll
            for (int k = 0; k < 4; ++k) pk[k] = ar[k];
#pragma unroll
            for (int k = 0; k < 4; ++k) pk[4 + k] = mc[k];
            out[i] = edge_mlp(pk, w1, b1, w2, b2v);
        }
    }
}

// ---- fallback: fp32 gather (only if workspace too small) ----------------
__global__ __launch_bounds__(256) void edge_decoder_f32_kernel(
    const float* __restrict__ zd, const float* __restrict__ zm,
    const int* __restrict__ row, const int* __restrict__ col,
    const float* __restrict__ w1, const float* __restrict__ b1,
    const float* __restrict__ w2, const float* __restrict__ b2,
    float* __restrict__ out, int E, int N)
{
    int i = blockIdx.x * blockDim.x + threadIdx.x;
    if (i >= E) return;
    int r = row[i];
    int c = col[i];
    if (r < 0) r = 0;
    if (r > N - 1) r = N - 1;
    if (c < 0) c = 0;
    if (c > N - 1) c = N - 1;
    const float* zdr = zd + (size_t)r * HIDDEN;
    const float* zmc = zm + (size_t)c * HIDDEN;
    float z[16];
#pragma unroll
    for (int k = 0; k < HIDDEN; ++k) z[k] = zdr[k];
#pragma unroll
    for (int k = 0; k < HIDDEN; ++k) z[HIDDEN + k] = zmc[k];
    float h[HIDDEN];
#pragma unroll
    for (int j = 0; j < HIDDEN; ++j) h[j] = b1[j];
#pragma unroll
    for (int k = 0; k < 2 * HIDDEN; ++k) {
        float zk = z[k];
#pragma unroll
        for (int j = 0; j < HIDDEN; ++j)
            h[j] = fmaf(zk, w1[k * HIDDEN + j], h[j]);
    }
    float logit = b2[0];
#pragma unroll
    for (int j = 0; j < HIDDEN; ++j) {
        float hj = h[j] > 0.0f ? h[j] : 0.0f;
        logit = fmaf(hj, w2[j], logit);
    }
    out[i] = 1.0f / (1.0f + expf(-logit));
}

extern "C" void kernel_launch(void* const* d_in, const int* in_sizes, int n_in,
                              void* d_out, int out_size, void* d_ws, size_t ws_size,
                              hipStream_t stream) {
    const float* zd  = (const float*)d_in[0];
    const float* zm  = (const float*)d_in[1];
    const int*   eli = (const int*)d_in[2];   // [2, E] flat: row then col
    const float* w1  = (const float*)d_in[3];
    const float* b1  = (const float*)d_in[4];
    const float* w2  = (const float*)d_in[5];
    const float* b2  = (const float*)d_in[6];
    float* out = (float*)d_out;

    int E = out_size;                 // 16,000,000
    int N = in_sizes[0] / HIDDEN;     // 100,000
    if (E <= 0 || N <= 0) return;

    const int* row = eli;
    const int* col = eli + E;
    const int block = 256;

    size_t tbl_bytes = (size_t)N * 4 * sizeof(unsigned);
    if (ws_size >= 2 * tbl_bytes) {
        unsigned* zdb = (unsigned*)d_ws;
        unsigned* zmb = zdb + (size_t)N * 4;

        int npairs = N * 4;
        int cgrid = (2 * npairs + block - 1) / block;
        convert_kernel<<<cgrid, block, 0, stream>>>(zd, zm, zdb, zmb, npairs);

        int nthreads = (E + 3) / 4;
        int grid = (nthreads + block - 1) / block;
        edge_decoder_bf16x4_kernel<<<grid, block, 0, stream>>>(
            zdb, zmb, row, col, w1, b1, w2, b2, out, E, N);
    } else {
        int grid = (E + block - 1) / block;
        edge_decoder_f32_kernel<<<grid, block, 0, stream>>>(
            zd, zm, row, col, w1, b1, w2, b2, out, E, N);
    }
}

// Round 8
// 313.752 us; speedup vs baseline: 1.3287x; 1.0535x over previous
//
#include <hip/hip_runtime.h>
#include <math.h>

#define HIDDEN 8

__device__ __forceinline__ unsigned pack_bf16_pair(float lo, float hi) {
    union { float f; unsigned u; } a, b;
    a.f = lo; b.f = hi;
    unsigned lr = (a.u + 0x7fffu + ((a.u >> 16) & 1u)) >> 16;          // rne
    unsigned hr = (b.u + 0x7fffu + ((b.u >> 16) & 1u)) & 0xffff0000u;  // rne
    return lr | hr;
}

// ---- precompute per-node partial pre-activations ------------------------
//   u[i] = zd[i] @ W1[0:8]          (8 fp32 -> 4 packed bf16 dwords)
//   v[i] = zm[i] @ W1[8:16] + b1    (8 fp32 -> 4 packed bf16 dwords)
__global__ __launch_bounds__(256) void precompute_uv_kernel(
    const float* __restrict__ zd, const float* __restrict__ zm,
    const float* __restrict__ w1, const float* __restrict__ b1,
    unsigned* __restrict__ u, unsigned* __restrict__ v, int N)
{
    int i = blockIdx.x * blockDim.x + threadIdx.x;
    if (i < N) {
        float x[HIDDEN];
#pragma unroll
        for (int k = 0; k < HIDDEN; ++k) x[k] = zd[i * HIDDEN + k];
        float acc[HIDDEN];
#pragma unroll
        for (int j = 0; j < HIDDEN; ++j) acc[j] = 0.0f;
#pragma unroll
        for (int k = 0; k < HIDDEN; ++k) {
#pragma unroll
            for (int j = 0; j < HIDDEN; ++j)
                acc[j] = fmaf(x[k], w1[k * HIDDEN + j], acc[j]);
        }
#pragma unroll
        for (int p = 0; p < 4; ++p)
            u[i * 4 + p] = pack_bf16_pair(acc[2 * p], acc[2 * p + 1]);
    } else if (i < 2 * N) {
        int q = i - N;
        float x[HIDDEN];
#pragma unroll
        for (int k = 0; k < HIDDEN; ++k) x[k] = zm[q * HIDDEN + k];
        float acc[HIDDEN];
#pragma unroll
        for (int j = 0; j < HIDDEN; ++j) acc[j] = b1[j];
#pragma unroll
        for (int k = 0; k < HIDDEN; ++k) {
#pragma unroll
            for (int j = 0; j < HIDDEN; ++j)
                acc[j] = fmaf(x[k], w1[(HIDDEN + k) * HIDDEN + j], acc[j]);
        }
#pragma unroll
        for (int p = 0; p < 4; ++p)
            v[q * 4 + p] = pack_bf16_pair(acc[2 * p], acc[2 * p + 1]);
    }
}

// ---- edge kernel: gather u_r, v_c; fused relu-dot + sigmoid -------------
__global__ __launch_bounds__(256) void edge_decoder_uv_kernel(
    const unsigned* __restrict__ u,   // [N,4] packed bf16 pairs
    const unsigned* __restrict__ v,   // [N,4]
    const int* __restrict__ row, const int* __restrict__ col,
    const float* __restrict__ w2, const float* __restrict__ b2,
    float* __restrict__ out, int E, int N)
{
    int i = blockIdx.x * blockDim.x + threadIdx.x;
    if (i >= E) return;

    int r = row[i];
    int c = col[i];
    if (r < 0) r = 0;
    if (r > N - 1) r = N - 1;
    if (c < 0) c = 0;
    if (c > N - 1) c = N - 1;

    const unsigned* ur = u + (size_t)r * 4;
    const unsigned* vc = v + (size_t)c * 4;

    unsigned pu[4], pv[4];
#pragma unroll
    for (int k = 0; k < 4; ++k) pu[k] = ur[k];
#pragma unroll
    for (int k = 0; k < 4; ++k) pv[k] = vc[k];

    float logit = b2[0];
#pragma unroll
    for (int k = 0; k < 4; ++k) {
        union { unsigned q; float f; } a0, a1, b0, b1u;
        a0.q = pu[k] << 16;
        a1.q = pu[k] & 0xffff0000u;
        b0.q = pv[k] << 16;
        b1u.q = pv[k] & 0xffff0000u;
        float h0 = a0.f + b0.f;
        float h1 = a1.f + b1u.f;
        if (h0 < 0.0f) h0 = 0.0f;
        if (h1 < 0.0f) h1 = 0.0f;
        logit = fmaf(h0, w2[2 * k], logit);
        logit = fmaf(h1, w2[2 * k + 1], logit);
    }

    out[i] = 1.0f / (1.0f + expf(-logit));
}

// ---- fallback: fp32 full MLP (only if workspace too small) --------------
__global__ __launch_bounds__(256) void edge_decoder_f32_kernel(
    const float* __restrict__ zd, const float* __restrict__ zm,
    const int* __restrict__ row, const int* __restrict__ col,
    const float* __restrict__ w1, const float* __restrict__ b1,
    const float* __restrict__ w2, const float* __restrict__ b2,
    float* __restrict__ out, int E, int N)
{
    int i = blockIdx.x * blockDim.x + threadIdx.x;
    if (i >= E) return;
    int r = row[i];
    int c = col[i];
    if (r < 0) r = 0;
    if (r > N - 1) r = N - 1;
    if (c < 0) c = 0;
    if (c > N - 1) c = N - 1;
    const float* zdr = zd + (size_t)r * HIDDEN;
    const float* zmc = zm + (size_t)c * HIDDEN;
    float z[16];
#pragma unroll
    for (int k = 0; k < HIDDEN; ++k) z[k] = zdr[k];
#pragma unroll
    for (int k = 0; k < HIDDEN; ++k) z[HIDDEN + k] = zmc[k];
    float h[HIDDEN];
#pragma unroll
    for (int j = 0; j < HIDDEN; ++j) h[j] = b1[j];
#pragma unroll
    for (int k = 0; k < 2 * HIDDEN; ++k) {
        float zk = z[k];
#pragma unroll
        for (int j = 0; j < HIDDEN; ++j)
            h[j] = fmaf(zk, w1[k * HIDDEN + j], h[j]);
    }
    float logit = b2[0];
#pragma unroll
    for (int j = 0; j < HIDDEN; ++j) {
        float hj = h[j] > 0.0f ? h[j] : 0.0f;
        logit = fmaf(hj, w2[j], logit);
    }
    out[i] = 1.0f / (1.0f + expf(-logit));
}

extern "C" void kernel_launch(void* const* d_in, const int* in_sizes, int n_in,
                              void* d_out, int out_size, void* d_ws, size_t ws_size,
                              hipStream_t stream) {
    const float* zd  = (const float*)d_in[0];
    const float* zm  = (const float*)d_in[1];
    const int*   eli = (const int*)d_in[2];   // [2, E] flat: row then col
    const float* w1  = (const float*)d_in[3];
    const float* b1  = (const float*)d_in[4];
    const float* w2  = (const float*)d_in[5];
    const float* b2  = (const float*)d_in[6];
    float* out = (float*)d_out;

    int E = out_size;                 // 16,000,000
    int N = in_sizes[0] / HIDDEN;     // 100,000
    if (E <= 0 || N <= 0) return;

    const int* row = eli;
    const int* col = eli + E;
    const int block = 256;

    size_t tbl_bytes = (size_t)N * 4 * sizeof(unsigned);   // 1.6 MB per table
    if (ws_size >= 2 * tbl_bytes) {
        unsigned* u = (unsigned*)d_ws;
        unsigned* v = u + (size_t)N * 4;

        int pgrid = (2 * N + block - 1) / block;
        precompute_uv_kernel<<<pgrid, block, 0, stream>>>(zd, zm, w1, b1, u, v, N);

        int grid = (E + block - 1) / block;
        edge_decoder_uv_kernel<<<grid, block, 0, stream>>>(
            u, v, row, col, w2, b2, out, E, N);
    } else {
        int grid = (E + block - 1) / block;
        edge_decoder_f32_kernel<<<grid, block, 0, stream>>>(
            zd, zm, row, col, w1, b1, w2, b2, out, E, N);
    }
}